// Round 3
// baseline (630.208 us; speedup 1.0000x reference)
//
#include <hip/hip_runtime.h>

typedef unsigned short u16;
typedef float f32x4 __attribute__((ext_vector_type(4)));
typedef short s16x8 __attribute__((ext_vector_type(8)));
typedef unsigned short u16x4 __attribute__((ext_vector_type(4)));

#define EPS 1e-6f

static __device__ __forceinline__ u16 f2bf(float f) {
  unsigned u = __float_as_uint(f);
  u += 0x7fffu + ((u >> 16) & 1u);   // RNE
  return (u16)(u >> 16);
}
static __device__ __forceinline__ float bf2f(u16 h) {
  return __uint_as_float(((unsigned)h) << 16);
}

// ---------------- Stage 1: transpose weights to bf16 [col][k] ----------------
__global__ void wtrans_kernel(const float* __restrict__ Wq, const float* __restrict__ Wk,
                              const float* __restrict__ Wv,
                              u16* __restrict__ WqT, u16* __restrict__ WkT, u16* __restrict__ WvT) {
  int b = blockIdx.x;
  int mat = b >> 4, cg = b & 15;
  const float* W = mat == 0 ? Wq : (mat == 1 ? Wk : Wv);
  u16* WT = mat == 0 ? WqT : (mat == 1 ? WkT : WvT);
  int t = threadIdx.x;
  int c = cg * 16 + (t & 15);
  int k0 = (t >> 4) * 16;
  for (int i = 0; i < 16; ++i) {
    int k = k0 + i;
    WT[c * 256 + k] = f2bf(W[k * 256 + c]);
  }
}

// ---------------- Stage 2: Q,K,V GEMMs ----------------
// 64-row tiles, 4 waves, 3 blocks/CU (LDS 53.2KB). Phase = one full matrix
// (4 waves x 64 cols). Single-buffered 256x32 weight chunk, staged 1 line per
// thread, register-prefetched one chunk ahead. Independent blocks cover each
// other's barrier stalls.
__global__ __launch_bounds__(256, 3)
void qkv_kernel(const float* __restrict__ x,
                const u16* __restrict__ WqT, const u16* __restrict__ WkT, const u16* __restrict__ WvT,
                const float* __restrict__ bq, const float* __restrict__ bk, const float* __restrict__ bv,
                u16* __restrict__ Qb, u16* __restrict__ Kt, u16* __restrict__ Vt,
                float* __restrict__ ksum, int N, int NPAD) {
  __shared__ u16 xs[64 * 256];    // swizzled: idx = row*256 + (col ^ ((row&7)<<3))  (32 KB)
  __shared__ u16 wst[256 * 40];   // weight chunk [col][32k + 8 pad]                (20.5 KB)
  const int tid = threadIdx.x;
  const int n0 = blockIdx.x * 64;

  // stage x tile (fp32 -> bf16), swizzled LDS writes
#pragma unroll
  for (int i = 0; i < 16; ++i) {
    int l = tid + i * 256;
    int row = l >> 6;
    int c4 = (l & 63) << 2;
    int n = n0 + row;
    float4 v = make_float4(0.f, 0.f, 0.f, 0.f);
    if (n < N) v = *(const float4*)(x + (size_t)n * 256 + c4);
    u16x4 pk;
    pk[0] = f2bf(v.x); pk[1] = f2bf(v.y); pk[2] = f2bf(v.z); pk[3] = f2bf(v.w);
    *(u16x4*)&xs[row * 256 + (c4 ^ ((row & 7) << 3))] = pk;
  }

  const int lane = tid & 63, wave = tid >> 6;
  const int quad = lane >> 4, l16 = lane & 15;
  const int wq = wave * 64;   // this wave's 64-col slice

  // prefetch chunk 0: thread owns col=tid, one 64B line (k 0..31)
  s16x8 w[4];
  {
    const u16* p0 = WqT + (size_t)tid * 256;
#pragma unroll
    for (int f = 0; f < 4; ++f) w[f] = *(const s16x8*)(p0 + f * 8);
  }

  for (int ph = 0; ph < 3; ++ph) {
    f32x4 acc[4][4] = {};
#pragma unroll
    for (int c = 0; c < 8; ++c) {
      __syncthreads();               // previous chunk's readers done (covers xs at it==0)
#pragma unroll
      for (int f = 0; f < 4; ++f) *(s16x8*)&wst[tid * 40 + f * 8] = w[f];
      const int it = ph * 8 + c;
      if (it + 1 < 24) {             // prefetch next chunk
        const int phn = (it + 1) >> 3, kcn = ((it + 1) & 7) * 32;
        const u16* WTn = phn == 0 ? WqT : (phn == 1 ? WkT : WvT);
        const u16* p = WTn + (size_t)tid * 256 + kcn;
#pragma unroll
        for (int f = 0; f < 4; ++f) w[f] = *(const s16x8*)(p + f * 8);
      }
      __syncthreads();               // chunk ready
      const int kc = c * 32;
      s16x8 a[4], b[4];
#pragma unroll
      for (int f = 0; f < 4; ++f) {
        int r = f * 16 + l16;
        a[f] = *(const s16x8*)&xs[r * 256 + ((kc + quad * 8) ^ ((r & 7) << 3))];
      }
#pragma unroll
      for (int f = 0; f < 4; ++f) b[f] = *(const s16x8*)&wst[(wq + f * 16 + l16) * 40 + quad * 8];
      if (ph == 0) {
        // swapped operands: C quad-dim = weight column -> vectorized row-major Q store
#pragma unroll
        for (int fr = 0; fr < 4; ++fr)
#pragma unroll
          for (int fc = 0; fc < 4; ++fc)
            acc[fr][fc] = __builtin_amdgcn_mfma_f32_16x16x32_bf16(b[fr], a[fc], acc[fr][fc], 0, 0, 0);
      } else {
#pragma unroll
        for (int fr = 0; fr < 4; ++fr)
#pragma unroll
          for (int fc = 0; fc < 4; ++fc)
            acc[fr][fc] = __builtin_amdgcn_mfma_f32_16x16x32_bf16(a[fr], b[fc], acc[fr][fc], 0, 0, 0);
      }
    }

    // ---- phase epilogue ----
    if (ph == 0) {
#pragma unroll
      for (int fw = 0; fw < 4; ++fw) {
        int colg4 = wq + fw * 16 + quad * 4;
        float4 bb = *(const float4*)(bq + colg4);
#pragma unroll
        for (int fx = 0; fx < 4; ++fx) {
          int n = n0 + fx * 16 + l16;
          u16x4 pk;
          pk[0] = f2bf(fmaxf(acc[fw][fx][0] + bb.x, 0.f));
          pk[1] = f2bf(fmaxf(acc[fw][fx][1] + bb.y, 0.f));
          pk[2] = f2bf(fmaxf(acc[fw][fx][2] + bb.z, 0.f));
          pk[3] = f2bf(fmaxf(acc[fw][fx][3] + bb.w, 0.f));
          if (n >= N) { pk[0] = 0; pk[1] = 0; pk[2] = 0; pk[3] = 0; }
          *(u16x4*)&Qb[(size_t)n * 256 + colg4] = pk;
        }
      }
    } else {
      const float* bias = (ph == 1) ? bk : bv;
      u16* T = (ph == 1) ? Kt : Vt;
      float ksacc[4] = {0.f, 0.f, 0.f, 0.f};
#pragma unroll
      for (int fc = 0; fc < 4; ++fc) {
        int colg = wq + fc * 16 + l16;
        float bb = bias[colg];
#pragma unroll
        for (int fr = 0; fr < 4; ++fr) {
          int n = n0 + fr * 16 + quad * 4;
          u16x4 pk;
#pragma unroll
          for (int j = 0; j < 4; ++j) {
            float v = acc[fr][fc][j] + bb;
            if (ph == 1) v = fmaxf(v, 0.f);
            bool ok = (n + j < N);
            pk[j] = ok ? f2bf(v) : (u16)0;
            if (ph == 1) ksacc[fc] += ok ? v : 0.f;
          }
          *(u16x4*)&T[(size_t)colg * NPAD + n] = pk;
        }
      }
      if (ph == 1) {
#pragma unroll
        for (int fc = 0; fc < 4; ++fc) {
          float v = ksacc[fc];
          v += __shfl_xor(v, 16);
          v += __shfl_xor(v, 32);
          if (quad == 0) atomicAdd(&ksum[wq + fc * 16 + l16], v);
        }
      }
    }
  }
}

// ---------------- Stage 3: KV^T partials — barrier-free, LDS-free streaming ----------------
// Each wave owns one 64x64 (e,d) tile and a split of n; fragments straight
// from global (full 64B lines, read-once data), depth-2 register prefetch.
__global__ __launch_bounds__(256, 3)
void kv_kernel(const u16* __restrict__ Kt, const u16* __restrict__ Vt,
               float* __restrict__ P, int NPAD, int S) {
  const int tid = threadIdx.x;
  const int s = blockIdx.x % S;
  const int g = blockIdx.x / S;
  const int ti = (g >> 1) * 128;  // e base
  const int tj = (g & 1) * 128;   // d base
  const int lane = tid & 63, wave = tid >> 6;
  const int quad = lane >> 4, l16 = lane & 15;
  const int we = (wave >> 1) * 64;
  const int wd = (wave & 1) * 64;
  const int NCH = NPAD >> 5;

  const u16* ap = Vt + (size_t)(ti + we + l16) * NPAD + quad * 8;
  const u16* bp = Kt + (size_t)(tj + wd + l16) * NPAD + quad * 8;

  f32x4 acc[4][4] = {};
  s16x8 xa[4], xb[4], ya[4], yb[4];

#define KVL(RA, RB, C) { size_t nb = (size_t)(C) << 5; \
  _Pragma("unroll") for (int f = 0; f < 4; ++f) RA[f] = *(const s16x8*)(ap + (size_t)f * 16 * NPAD + nb); \
  _Pragma("unroll") for (int f = 0; f < 4; ++f) RB[f] = *(const s16x8*)(bp + (size_t)f * 16 * NPAD + nb); }

#define KVM(RA, RB) { \
  _Pragma("unroll") for (int fr = 0; fr < 4; ++fr) \
  _Pragma("unroll") for (int fc = 0; fc < 4; ++fc) \
    acc[fr][fc] = __builtin_amdgcn_mfma_f32_16x16x32_bf16(RA[fr], RB[fc], acc[fr][fc], 0, 0, 0); }

  int c = s;
  if (c < NCH) KVL(xa, xb, c);
  if (c + S < NCH) KVL(ya, yb, c + S);
  for (; c < NCH; c += 2 * S) {
    KVM(xa, xb);
    if (c + 2 * S < NCH) KVL(xa, xb, c + 2 * S);
    if (c + S < NCH) {
      KVM(ya, yb);
      if (c + 3 * S < NCH) KVL(ya, yb, c + 3 * S);
    }
  }

  float* Pp = P + (size_t)s * 65536;
#pragma unroll
  for (int fr = 0; fr < 4; ++fr)
#pragma unroll
    for (int fc = 0; fc < 4; ++fc) {
      int d = tj + wd + fc * 16 + l16;
      int e0 = ti + we + fr * 16 + quad * 4;
      *(f32x4*)&Pp[(size_t)d * 256 + e0] = acc[fr][fc];
    }
}

// ---------------- Stage 4: reduce partials, emit KVtb[e][d] bf16 ----------------
__global__ void kvred_kernel(const float* __restrict__ P, u16* __restrict__ KVtb, int nsp) {
  int d = blockIdx.x;
  int e = threadIdx.x;
  float s = 0.f;
  for (int sp = 0; sp < nsp; ++sp) s += P[(size_t)sp * 65536 + d * 256 + e];
  KVtb[e * 256 + d] = f2bf(s);
}

// ---------------- Stage 5: out[r][e] = (Q@KV)[r][e] / (Q[r].ksum + eps) ----------------
// 64-row Q tile in LDS; KV (128 KB, L2-hot) read direct from global with
// depth-2 prefetch. Zero barriers in the MFMA loop.
__global__ __launch_bounds__(256, 3)
void out_kernel(const u16* __restrict__ Qb, const u16* __restrict__ KVtb,
                const float* __restrict__ ksum, float* __restrict__ out,
                int N, int NPAD) {
  __shared__ u16 Qs[64 * 256];   // swizzled
  __shared__ float ks[256];
  __shared__ float nrmp[256];
  __shared__ float nrm[64];
  const int tid = threadIdx.x;
  const int r0 = blockIdx.x * 64;

#pragma unroll
  for (int i = 0; i < 8; ++i) {
    int l = tid + i * 256;
    int row = l >> 5;
    int seg = (l & 31) << 3;
    *(s16x8*)&Qs[row * 256 + (seg ^ ((row & 7) << 3))] =
        *(const s16x8*)&Qb[(size_t)(r0 + row) * 256 + seg];
  }
  ks[tid] = ksum[tid];
  __syncthreads();

  // normalizer: 4 threads per row
  {
    int r = tid >> 2, h = tid & 3;
    float sa = 0.f;
#pragma unroll
    for (int dd = 0; dd < 64; dd += 8) {
      int dseg = h * 64 + dd;
      s16x8 q = *(const s16x8*)&Qs[r * 256 + (dseg ^ ((r & 7) << 3))];
#pragma unroll
      for (int j = 0; j < 8; ++j) sa += bf2f((u16)q[j]) * ks[dseg + j];
    }
    nrmp[tid] = sa;
  }
  __syncthreads();
  if (tid < 64)
    nrm[tid] = nrmp[4 * tid] + nrmp[4 * tid + 1] + nrmp[4 * tid + 2] + nrmp[4 * tid + 3] + EPS;
  __syncthreads();

  const int lane = tid & 63, wave = tid >> 6;
  const int quad = lane >> 4, l16 = lane & 15;
  const int we = wave * 64;   // this wave's 64-e slice

  const u16* ap = KVtb + (size_t)(we + l16) * 256 + quad * 8;

  f32x4 acc[4][4] = {};
  s16x8 xa[4], ya[4];
#define OL(RA, C) { int kc = (C) * 32; \
  _Pragma("unroll") for (int f = 0; f < 4; ++f) RA[f] = *(const s16x8*)(ap + f * 16 * 256 + kc); }
#define OM(RA, C) { int kc = (C) * 32; s16x8 b[4]; \
  _Pragma("unroll") for (int f = 0; f < 4; ++f) { int r = f * 16 + l16; \
    b[f] = *(const s16x8*)&Qs[r * 256 + ((kc + quad * 8) ^ ((r & 7) << 3))]; } \
  _Pragma("unroll") for (int fr = 0; fr < 4; ++fr) \
  _Pragma("unroll") for (int fc = 0; fc < 4; ++fc) \
    acc[fr][fc] = __builtin_amdgcn_mfma_f32_16x16x32_bf16(RA[fr], b[fc], acc[fr][fc], 0, 0, 0); }

  OL(xa, 0);
  OL(ya, 1);
#pragma unroll
  for (int c = 0; c < 8; c += 2) {
    OM(xa, c);
    if (c + 2 < 8) OL(xa, c + 2);
    OM(ya, c + 1);
    if (c + 3 < 8) OL(ya, c + 3);
  }

#pragma unroll
  for (int fc = 0; fc < 4; ++fc) {
    int rl = fc * 16 + l16;
    int rg = r0 + rl;
    float inv = 1.0f / nrm[rl];
    if (rg < N) {
#pragma unroll
      for (int fr = 0; fr < 4; ++fr) {
        int eg = we + fr * 16 + quad * 4;
        f32x4 o;
        o[0] = acc[fr][fc][0] * inv;
        o[1] = acc[fr][fc][1] * inv;
        o[2] = acc[fr][fc][2] * inv;
        o[3] = acc[fr][fc][3] * inv;
        *(f32x4*)&out[(size_t)rg * 256 + eg] = o;
      }
    }
  }
}

extern "C" void kernel_launch(void* const* d_in, const int* in_sizes, int n_in,
                              void* d_out, int out_size, void* d_ws, size_t ws_size,
                              hipStream_t stream) {
  const float* x  = (const float*)d_in[0];
  const float* Wq = (const float*)d_in[1];
  const float* bq = (const float*)d_in[2];
  const float* Wk = (const float*)d_in[3];
  const float* bk = (const float*)d_in[4];
  const float* Wv = (const float*)d_in[5];
  const float* bv = (const float*)d_in[6];
  float* out = (float*)d_out;

  int N = in_sizes[0] / 256;
  int NPAD = ((N + 63) / 64) * 64;
  int nblk = NPAD / 64;

  size_t szT = (size_t)256 * NPAD * sizeof(u16);
  size_t fixed = 3 * szT + (size_t)65536 * sizeof(u16) + 256 * sizeof(float)
               + 3 * (size_t)65536 * sizeof(u16);
  int S = 192;
  if (fixed + (size_t)S * 65536 * sizeof(float) > ws_size) S = 128;
  if (fixed + (size_t)S * 65536 * sizeof(float) > ws_size) S = 64;

  char* p = (char*)d_ws;
  u16* Kt = (u16*)p; p += szT;
  u16* Vt = (u16*)p; p += szT;
  u16* Qb = (u16*)p; p += szT;
  float* P = (float*)p; p += (size_t)S * 65536 * sizeof(float);
  u16* KVtb = (u16*)p; p += (size_t)65536 * sizeof(u16);
  float* ksum = (float*)p; p += 256 * sizeof(float);
  u16* WqT = (u16*)p; p += (size_t)65536 * sizeof(u16);
  u16* WkT = (u16*)p; p += (size_t)65536 * sizeof(u16);
  u16* WvT = (u16*)p; p += (size_t)65536 * sizeof(u16);

  hipMemsetAsync(ksum, 0, 256 * sizeof(float), stream);
  wtrans_kernel<<<48, 256, 0, stream>>>(Wq, Wk, Wv, WqT, WkT, WvT);
  qkv_kernel<<<nblk, 256, 0, stream>>>(x, WqT, WkT, WvT, bq, bk, bv, Qb, Kt, Vt, ksum, N, NPAD);
  kv_kernel<<<S * 4, 256, 0, stream>>>(Kt, Vt, P, NPAD, S);
  kvred_kernel<<<256, 256, 0, stream>>>(P, KVtb, S);
  out_kernel<<<nblk, 256, 0, stream>>>(Qb, KVtb, ksum, out, N, NPAD);
}

// Round 4
// 427.887 us; speedup vs baseline: 1.4728x; 1.4728x over previous
//
#include <hip/hip_runtime.h>

typedef unsigned short u16;
typedef float f32x4 __attribute__((ext_vector_type(4)));
typedef short s16x8 __attribute__((ext_vector_type(8)));
typedef unsigned short u16x4 __attribute__((ext_vector_type(4)));

#define EPS 1e-6f

static __device__ __forceinline__ u16 f2bf(float f) {
  unsigned u = __float_as_uint(f);
  u += 0x7fffu + ((u >> 16) & 1u);   // RNE
  return (u16)(u >> 16);
}
static __device__ __forceinline__ float bf2f(u16 h) {
  return __uint_as_float(((unsigned)h) << 16);
}

// ---------------- Stage 1: transpose weights to bf16, PRE-SWIZZLED ----------------
// WT u16-index = (c*256 + k) ^ ((c&7)<<3)  -> linear LDS copy yields swizzled
// image; swizzled ds_read_b128 is bank-conflict-free.
__global__ void wtrans_kernel(const float* __restrict__ Wq, const float* __restrict__ Wk,
                              const float* __restrict__ Wv,
                              u16* __restrict__ WqT, u16* __restrict__ WkT, u16* __restrict__ WvT) {
  int b = blockIdx.x;
  int mat = b >> 4, cg = b & 15;
  const float* W = mat == 0 ? Wq : (mat == 1 ? Wk : Wv);
  u16* WT = mat == 0 ? WqT : (mat == 1 ? WkT : WvT);
  int t = threadIdx.x;
  int c = cg * 16 + (t & 15);
  int k0 = (t >> 4) * 16;
  for (int i = 0; i < 16; ++i) {
    int k = k0 + i;
    WT[(c * 256 + k) ^ ((c & 7) << 3)] = f2bf(W[k * 256 + c]);
  }
}

// ---------------- Stage 2: Q,K,V GEMMs ----------------
// 128-row tile, 512 thr (8 waves = 2 rowg x 4 colg), 1 blk/CU (130KB LDS).
// Phase = one 128-col weight half (64KB in LDS, 6 phases, 12 barriers/block).
// Register prefetch issued at phase start (full-phase slack before drain);
// epilogue of phase p-1 deferred past phase p's barriers (store-drain slack).
__global__ __launch_bounds__(512, 2)
void qkv_kernel(const float* __restrict__ x,
                const u16* __restrict__ WqT, const u16* __restrict__ WkT, const u16* __restrict__ WvT,
                const float* __restrict__ bq, const float* __restrict__ bk, const float* __restrict__ bv,
                u16* __restrict__ Qb, u16* __restrict__ Kt, u16* __restrict__ Vt,
                float* __restrict__ ksum, int N, int NPAD) {
  __shared__ u16 xs[128][264];    // x tile bf16, +8 pad (67.5 KB)
  __shared__ u16 wsh[128 * 256];  // swizzled weight half (64 KB)
  const int tid = threadIdx.x;
  const int n0 = blockIdx.x * 128;

  // prefetch phase-0 weight half FIRST (flies during x-stage)
  s16x8 w[8];
  {
    const u16* p = WqT + tid * 8;
#pragma unroll
    for (int f = 0; f < 8; ++f) w[f] = *(const s16x8*)(p + f * 4096);
  }

  // stage x tile (fp32 -> bf16)
#pragma unroll
  for (int i = 0; i < 16; ++i) {
    int l = tid + i * 512;
    int row = l >> 6;
    int c4 = (l & 63) << 2;
    int n = n0 + row;
    float4 v = make_float4(0.f, 0.f, 0.f, 0.f);
    if (n < N) v = *(const float4*)(x + (size_t)n * 256 + c4);
    u16x4 pk;
    pk[0] = f2bf(v.x); pk[1] = f2bf(v.y); pk[2] = f2bf(v.z); pk[3] = f2bf(v.w);
    *(u16x4*)&xs[row][c4] = pk;
  }

  const int lane = tid & 63, wave = tid >> 6;
  const int quad = lane >> 4, l16 = lane & 15;
  const int wr = (wave & 1) * 64;     // row group (64 rows)
  const int clb = (wave >> 1) * 32;   // local col base within 128 (4 groups of 32)

  f32x4 accP[4][2];
  int matP = 0, colBP = 0;

  auto epilogue = [&](int matE, int colBE, f32x4 (&ac)[4][2]) {
    if (matE == 0) {
      // swapped orientation: quad-dim = weight col, l16-dim = x row
#pragma unroll
      for (int fc = 0; fc < 2; ++fc) {
        int colg4 = colBE + clb + fc * 16 + quad * 4;
        float4 bb = *(const float4*)(bq + colg4);
#pragma unroll
        for (int fr = 0; fr < 4; ++fr) {
          int n = n0 + wr + fr * 16 + l16;
          u16x4 pk;
          pk[0] = f2bf(fmaxf(ac[fr][fc][0] + bb.x, 0.f));
          pk[1] = f2bf(fmaxf(ac[fr][fc][1] + bb.y, 0.f));
          pk[2] = f2bf(fmaxf(ac[fr][fc][2] + bb.z, 0.f));
          pk[3] = f2bf(fmaxf(ac[fr][fc][3] + bb.w, 0.f));
          if (n >= N) { pk[0] = 0; pk[1] = 0; pk[2] = 0; pk[3] = 0; }
          *(u16x4*)&Qb[(size_t)n * 256 + colg4] = pk;
        }
      }
    } else {
      u16* T = (matE == 1) ? Kt : Vt;
      const float* bias = (matE == 1) ? bk : bv;
      float ksacc[2] = {0.f, 0.f};
#pragma unroll
      for (int fc = 0; fc < 2; ++fc) {
        int colg = colBE + clb + fc * 16 + l16;
        float bb = bias[colg];
#pragma unroll
        for (int fr = 0; fr < 4; ++fr) {
          int n = n0 + wr + fr * 16 + quad * 4;
          u16x4 pk;
#pragma unroll
          for (int j = 0; j < 4; ++j) {
            float v = ac[fr][fc][j] + bb;
            if (matE == 1) v = fmaxf(v, 0.f);
            bool ok = (n + j < N);
            pk[j] = ok ? f2bf(v) : (u16)0;
            if (matE == 1) ksacc[fc] += ok ? v : 0.f;
          }
          *(u16x4*)&T[(size_t)colg * NPAD + n] = pk;
        }
      }
      if (matE == 1) {
#pragma unroll
        for (int fc = 0; fc < 2; ++fc) {
          float v = ksacc[fc];
          v += __shfl_xor(v, 16);
          v += __shfl_xor(v, 32);
          if (quad == 0) atomicAdd(&ksum[colBE + clb + fc * 16 + l16], v);
        }
      }
    }
  };

  for (int ph = 0; ph < 6; ++ph) {
    const int mat = ph >> 1, colB = (ph & 1) * 128;

    __syncthreads();                 // readers of previous wsh done
#pragma unroll
    for (int f = 0; f < 8; ++f) *(s16x8*)&wsh[f * 4096 + tid * 8] = w[f];
    __syncthreads();                 // wsh ready (covers xs at ph==0)

    if (ph + 1 < 6) {                // prefetch next half: full-phase slack
      int matn = (ph + 1) >> 1, colBn = ((ph + 1) & 1) * 128;
      const u16* WTn = matn == 0 ? WqT : (matn == 1 ? WkT : WvT);
      const u16* p = WTn + colBn * 256 + tid * 8;
#pragma unroll
      for (int f = 0; f < 8; ++f) w[f] = *(const s16x8*)(p + f * 4096);
    }

    if (ph > 0) epilogue(matP, colBP, accP);   // stores drain at NEXT barrier

    f32x4 acc[4][2] = {};
#pragma unroll
    for (int c = 0; c < 8; ++c) {
      const int kc = c * 32;
      s16x8 a[4], b[2];
#pragma unroll
      for (int f = 0; f < 4; ++f) a[f] = *(const s16x8*)&xs[wr + f * 16 + l16][kc + quad * 8];
#pragma unroll
      for (int f = 0; f < 2; ++f) {
        int cl = clb + f * 16 + l16;
        b[f] = *(const s16x8*)&wsh[(cl * 256 + kc + quad * 8) ^ ((cl & 7) << 3)];
      }
      if (mat == 0) {
#pragma unroll
        for (int fr = 0; fr < 4; ++fr)
#pragma unroll
          for (int fc = 0; fc < 2; ++fc)
            acc[fr][fc] = __builtin_amdgcn_mfma_f32_16x16x32_bf16(b[fc], a[fr], acc[fr][fc], 0, 0, 0);
      } else {
#pragma unroll
        for (int fr = 0; fr < 4; ++fr)
#pragma unroll
          for (int fc = 0; fc < 2; ++fc)
            acc[fr][fc] = __builtin_amdgcn_mfma_f32_16x16x32_bf16(a[fr], b[fc], acc[fr][fc], 0, 0, 0);
      }
    }
#pragma unroll
    for (int fr = 0; fr < 4; ++fr)
#pragma unroll
      for (int fc = 0; fc < 2; ++fc) accP[fr][fc] = acc[fr][fc];
    matP = mat; colBP = colB;
  }
  epilogue(matP, colBP, accP);
}

// ---------------- Stage 3: KV^T partials — barrier-free, LDS-free streaming ----------------
// Wave-owned 64x64 tiles; 64-element n-chunks = full 128B per row per visit.
__global__ __launch_bounds__(256, 3)
void kv_kernel(const u16* __restrict__ Kt, const u16* __restrict__ Vt,
               float* __restrict__ P, int NPAD, int S) {
  const int tid = threadIdx.x;
  const int s = blockIdx.x % S;
  const int g = blockIdx.x / S;
  const int ti = (g >> 1) * 128;  // e base (Vt)
  const int tj = (g & 1) * 128;   // d base (Kt)
  const int lane = tid & 63, wave = tid >> 6;
  const int quad = lane >> 4, l16 = lane & 15;
  const int we = (wave >> 1) * 64;
  const int wd = (wave & 1) * 64;
  const int NC64 = NPAD >> 6;

  const u16* ap = Vt + (size_t)(ti + we + l16) * NPAD + quad * 8;
  const u16* bp = Kt + (size_t)(tj + wd + l16) * NPAD + quad * 8;

  f32x4 acc[4][4] = {};
  for (int c = s; c < NC64; c += S) {
    size_t nb = (size_t)c << 6;
    s16x8 a0[4], a1[4], b0[4], b1[4];
#pragma unroll
    for (int f = 0; f < 4; ++f) {
      const u16* ar = ap + (size_t)f * 16 * NPAD + nb;
      const u16* br = bp + (size_t)f * 16 * NPAD + nb;
      a0[f] = *(const s16x8*)ar; a1[f] = *(const s16x8*)(ar + 32);
      b0[f] = *(const s16x8*)br; b1[f] = *(const s16x8*)(br + 32);
    }
#pragma unroll
    for (int fr = 0; fr < 4; ++fr)
#pragma unroll
      for (int fc = 0; fc < 4; ++fc)
        acc[fr][fc] = __builtin_amdgcn_mfma_f32_16x16x32_bf16(a0[fr], b0[fc], acc[fr][fc], 0, 0, 0);
#pragma unroll
    for (int fr = 0; fr < 4; ++fr)
#pragma unroll
      for (int fc = 0; fc < 4; ++fc)
        acc[fr][fc] = __builtin_amdgcn_mfma_f32_16x16x32_bf16(a1[fr], b1[fc], acc[fr][fc], 0, 0, 0);
  }

  float* Pp = P + (size_t)s * 65536;
#pragma unroll
  for (int fr = 0; fr < 4; ++fr)
#pragma unroll
    for (int fc = 0; fc < 4; ++fc) {
      int d = tj + wd + fc * 16 + l16;
      int e0 = ti + we + fr * 16 + quad * 4;
      *(f32x4*)&Pp[(size_t)d * 256 + e0] = acc[fr][fc];
    }
}

// ---------------- Stage 4: reduce partials, emit KVtb[e][d] bf16 ----------------
__global__ void kvred_kernel(const float* __restrict__ P, u16* __restrict__ KVtb, int nsp) {
  int d = blockIdx.x;
  int e = threadIdx.x;
  float s = 0.f;
  for (int sp = 0; sp < nsp; ++sp) s += P[(size_t)sp * 65536 + d * 256 + e];
  KVtb[e * 256 + d] = f2bf(s);
}

// ---------------- Stage 5: out[r][e] = (Q@KV)[r][e] / (Q[r].ksum + eps) ----------------
// 64-row Q tile, 256 thr, 4 blk/CU; KVtb (128KB, L2-hot) direct from global.
// Zero barriers in the MFMA loop.
__global__ __launch_bounds__(256, 4)
void out_kernel(const u16* __restrict__ Qb, const u16* __restrict__ KVtb,
                const float* __restrict__ ksum, float* __restrict__ out,
                int N, int NPAD) {
  __shared__ u16 Qs[64][264];
  __shared__ float ks[256];
  __shared__ float nrmp[256];
  __shared__ float nrm[64];
  const int tid = threadIdx.x;
  const int r0 = blockIdx.x * 64;

#pragma unroll
  for (int i = 0; i < 8; ++i) {
    int l = tid + i * 256;
    int row = l >> 5;
    int seg = (l & 31) << 3;
    *(s16x8*)&Qs[row][seg] = *(const s16x8*)&Qb[(size_t)(r0 + row) * 256 + seg];
  }
  ks[tid] = ksum[tid];
  __syncthreads();

  // normalizer: 4 threads per row
  {
    int r = tid & 63, h = tid >> 6;
    float sa = 0.f;
#pragma unroll
    for (int dd = 0; dd < 64; dd += 8) {
      int d = h * 64 + dd;
      s16x8 q = *(const s16x8*)&Qs[r][d];
#pragma unroll
      for (int j = 0; j < 8; ++j) sa += bf2f((u16)q[j]) * ks[d + j];
    }
    nrmp[tid] = sa;
  }
  __syncthreads();
  if (tid < 64)
    nrm[tid] = nrmp[tid] + nrmp[tid + 64] + nrmp[tid + 128] + nrmp[tid + 192] + EPS;
  __syncthreads();

  const int lane = tid & 63, wave = tid >> 6;
  const int quad = lane >> 4, l16 = lane & 15;
  const int eg = wave * 64;   // this wave's 64-e slice

  const u16* ap = KVtb + (size_t)(eg + l16) * 256 + quad * 8;

  f32x4 acc[4][4] = {};
#pragma unroll 2
  for (int c = 0; c < 8; ++c) {
    int kc = c * 32;
    s16x8 a[4], b[4];
#pragma unroll
    for (int f = 0; f < 4; ++f) a[f] = *(const s16x8*)(ap + f * 16 * 256 + kc);
#pragma unroll
    for (int f = 0; f < 4; ++f) b[f] = *(const s16x8*)&Qs[f * 16 + l16][kc + quad * 8];
#pragma unroll
    for (int fr = 0; fr < 4; ++fr)
#pragma unroll
      for (int fc = 0; fc < 4; ++fc)
        acc[fr][fc] = __builtin_amdgcn_mfma_f32_16x16x32_bf16(a[fr], b[fc], acc[fr][fc], 0, 0, 0);
  }

#pragma unroll
  for (int fc = 0; fc < 4; ++fc) {
    int rl = fc * 16 + l16;
    int rg = r0 + rl;
    float inv = 1.0f / nrm[rl];
    if (rg < N) {
#pragma unroll
      for (int fr = 0; fr < 4; ++fr) {
        int e0 = eg + fr * 16 + quad * 4;
        f32x4 o;
        o[0] = acc[fr][fc][0] * inv;
        o[1] = acc[fr][fc][1] * inv;
        o[2] = acc[fr][fc][2] * inv;
        o[3] = acc[fr][fc][3] * inv;
        *(f32x4*)&out[(size_t)rg * 256 + e0] = o;
      }
    }
  }
}

extern "C" void kernel_launch(void* const* d_in, const int* in_sizes, int n_in,
                              void* d_out, int out_size, void* d_ws, size_t ws_size,
                              hipStream_t stream) {
  const float* x  = (const float*)d_in[0];
  const float* Wq = (const float*)d_in[1];
  const float* bq = (const float*)d_in[2];
  const float* Wk = (const float*)d_in[3];
  const float* bk = (const float*)d_in[4];
  const float* Wv = (const float*)d_in[5];
  const float* bv = (const float*)d_in[6];
  float* out = (float*)d_out;

  int N = in_sizes[0] / 256;
  int NPAD = ((N + 127) / 128) * 128;
  int nblkQ = NPAD / 128;
  int nblkO = NPAD / 64;

  size_t szT = (size_t)256 * NPAD * sizeof(u16);
  size_t fixed = 3 * szT + (size_t)65536 * sizeof(u16) + 256 * sizeof(float)
               + 3 * (size_t)65536 * sizeof(u16);
  int S = 128;
  if (fixed + (size_t)S * 65536 * sizeof(float) > ws_size) S = 64;
  if (fixed + (size_t)S * 65536 * sizeof(float) > ws_size) S = 32;

  char* p = (char*)d_ws;
  u16* Kt = (u16*)p; p += szT;
  u16* Vt = (u16*)p; p += szT;
  u16* Qb = (u16*)p; p += szT;
  float* P = (float*)p; p += (size_t)S * 65536 * sizeof(float);
  u16* KVtb = (u16*)p; p += (size_t)65536 * sizeof(u16);
  float* ksum = (float*)p; p += 256 * sizeof(float);
  u16* WqT = (u16*)p; p += (size_t)65536 * sizeof(u16);
  u16* WkT = (u16*)p; p += (size_t)65536 * sizeof(u16);
  u16* WvT = (u16*)p; p += (size_t)65536 * sizeof(u16);

  hipMemsetAsync(ksum, 0, 256 * sizeof(float), stream);
  wtrans_kernel<<<48, 256, 0, stream>>>(Wq, Wk, Wv, WqT, WkT, WvT);
  qkv_kernel<<<nblkQ, 512, 0, stream>>>(x, WqT, WkT, WvT, bq, bk, bv, Qb, Kt, Vt, ksum, N, NPAD);
  kv_kernel<<<S * 4, 256, 0, stream>>>(Kt, Vt, P, NPAD, S);
  kvred_kernel<<<256, 256, 0, stream>>>(P, KVtb, S);
  out_kernel<<<nblkO, 256, 0, stream>>>(Qb, KVtb, ksum, out, N, NPAD);
}